// Round 9
// baseline (691.700 us; speedup 1.0000x reference)
//
#include <hip/hip_runtime.h>
#include <hip/hip_bf16.h>

typedef __attribute__((ext_vector_type(8))) short short8;
typedef __attribute__((ext_vector_type(4))) float f32x4;
typedef __attribute__((ext_vector_type(16))) float f32x16;
typedef __attribute__((ext_vector_type(4))) unsigned int u32x4;

#define MFMA32(A, B, C) __builtin_amdgcn_mfma_f32_32x32x16_bf16((A), (B), (C), 0, 0, 0)

__device__ __forceinline__ short f2bf(float x) {
  unsigned u = __float_as_uint(x);
  return (short)((u + 0x7FFFu + ((u >> 16) & 1u)) >> 16);  // RNE; inputs finite
}

__device__ __forceinline__ unsigned cvtpk(float lo, float hi) {
  unsigned r;
  asm("v_cvt_pk_bf16_f32 %0, %1, %2" : "=v"(r) : "v"(lo), "v"(hi));
  return r;
}

__device__ __forceinline__ void gload16(const void* g, const void* s) {
  __builtin_amdgcn_global_load_lds(
      (const __attribute__((address_space(1))) unsigned int*)g,
      (__attribute__((address_space(3))) unsigned int*)s, 16, 0, 0);
}

// ---------------- weight transpose + bf16 convert: W[1024][128] -> WT[128][1024] ----------------
__global__ __launch_bounds__(256) void wt_kernel(
    const float* __restrict__ Wq, const float* __restrict__ Wk, const float* __restrict__ Wv,
    short* __restrict__ WqT, short* __restrict__ WkT, short* __restrict__ WvT)
{
  const float* W  = (blockIdx.y == 0) ? Wq  : (blockIdx.y == 1) ? Wk  : Wv;
  short*       WT = (blockIdx.y == 0) ? WqT : (blockIdx.y == 1) ? WkT : WvT;
  int idx = blockIdx.x * 256 + threadIdx.x;   // 0..131071
  int n = idx >> 10, k = idx & 1023;
  WT[idx] = f2bf(W[k * 128 + n]);
}

// ---------------- fused QKV projection: stream-contiguous NT staging + LDS redistribute ----------
// Block: 32 rows x 128 cols, 4 waves; wave w owns n = w*32 + l31 (one 32x32 acc).
// Per phase (K=256 fp32): each lane NT-loads 32 B contiguous; a wave covers whole 1 KB row-chunks
// (DRAM-stream granularity). Convert to bf16 in-reg, ds_write to XOR-swizzled [32][256] bf16 tile,
// double-buffered. T14: next-phase loads issued BEFORE compute; vmcnt(0)+ds_write after; 1 barrier.
__global__ __launch_bounds__(256, 4) void proj_kernel(
    const float* __restrict__ Aq, const float* __restrict__ Ak, const float* __restrict__ Av,
    const short* __restrict__ WqT, const short* __restrict__ WkT, const short* __restrict__ WvT,
    const float* __restrict__ bq, const float* __restrict__ bk, const float* __restrict__ bv,
    short* __restrict__ Qs, short* __restrict__ Ks, short* __restrict__ VTs,
    float scale_q)
{
  __shared__ short lds[16384];   // 2 bufs x ([32][256] bf16 swizzled = 16 KB)
  const int y = blockIdx.y;
  const float* A    = (y == 0) ? Aq  : (y == 1) ? Ak  : Av;
  const short* WT   = (y == 0) ? WqT : (y == 1) ? WkT : WvT;
  const float* bias = (y == 0) ? bq  : (y == 1) ? bk  : bv;
  const int tid = threadIdx.x, l = tid & 63, w = tid >> 6;
  const int l31 = l & 31, hi = l >> 5;
  const long m0 = (long)blockIdx.x * 32;

  // staging: round rr covers rows rr*8 .. rr*8+7; this thread: row srow+rr*8, 32 B at scol
  const int srow = w * 2 + (l >> 5);
  const int scol = (l & 31) * 8;             // floats; lane covers 32 B contiguous
  const float* As = A + (m0 + srow) * 1024 + scol;
  const int swb = ((l & 31) * 16);           // ds_write byte within row (before XOR)

  f32x4 sa0, sa1, sa2, sa3, sb0, sb1, sb2, sb3;

  #define PISSUE() { \
    sa0 = __builtin_nontemporal_load((const f32x4*)(Asx));        \
    sb0 = __builtin_nontemporal_load((const f32x4*)(Asx + 4));    \
    sa1 = __builtin_nontemporal_load((const f32x4*)(Asx + 8192)); \
    sb1 = __builtin_nontemporal_load((const f32x4*)(Asx + 8196)); \
    sa2 = __builtin_nontemporal_load((const f32x4*)(Asx + 16384));\
    sb2 = __builtin_nontemporal_load((const f32x4*)(Asx + 16388));\
    sa3 = __builtin_nontemporal_load((const f32x4*)(Asx + 24576));\
    sb3 = __builtin_nontemporal_load((const f32x4*)(Asx + 24580));}

  #define PWRITE(bb) { \
    _Pragma("unroll") \
    for (int rr = 0; rr < 4; ++rr) { \
      const f32x4 va = (rr == 0) ? sa0 : (rr == 1) ? sa1 : (rr == 2) ? sa2 : sa3; \
      const f32x4 vb = (rr == 0) ? sb0 : (rr == 1) ? sb1 : (rr == 2) ? sb2 : sb3; \
      u32x4 pk_; \
      pk_[0] = cvtpk(va[0], va[1]); pk_[1] = cvtpk(va[2], va[3]); \
      pk_[2] = cvtpk(vb[0], vb[1]); pk_[3] = cvtpk(vb[2], vb[3]); \
      const int r_ = rr * 8 + srow; \
      *(u32x4*)((char*)lds + (bb) * 16384 + r_ * 512 + (swb ^ ((r_ & 15) << 4))) = pk_; \
    } }

  f32x16 acc = {};
  const int n_ = w * 32 + l31;
  const short* Wn = WT + (long)n_ * 1024 + hi * 8;
  const char* ab0 = (const char*)lds + l31 * 512;
  const int swz = (l31 & 15) << 4;

  // prologue: stage phase 0
  {
    const float* Asx = As;
    PISSUE();
    asm volatile("s_waitcnt vmcnt(0)" ::: "memory");
    PWRITE(0);
    asm volatile("s_waitcnt lgkmcnt(0)" ::: "memory");
    __builtin_amdgcn_s_barrier();
  }

  #pragma unroll
  for (int kc = 0; kc < 4; ++kc) {
    const int bb = kc & 1;
    if (kc + 1 < 4) {
      const float* Asx = As + (kc + 1) * 256;
      PISSUE();
    }
    const char* ab = ab0 + bb * 16384;
    if (y < 2) {
      #pragma unroll
      for (int k16 = 0; k16 < 16; ++k16) {
        short8 af = *(const short8*)(ab + ((k16 * 32 + hi * 16) ^ swz));
        short8 wb = *(const short8*)(Wn + kc * 256 + k16 * 16);
        acc = MFMA32(af, wb, acc);
      }
    } else {
      #pragma unroll
      for (int k16 = 0; k16 < 16; ++k16) {
        short8 af = *(const short8*)(ab + ((k16 * 32 + hi * 16) ^ swz));
        short8 wb = *(const short8*)(Wn + kc * 256 + k16 * 16);
        // V^T: A-operand = W^T rows (dv), B-operand = value rows as columns
        acc = MFMA32(wb, af, acc);
      }
    }
    if (kc + 1 < 4) {
      asm volatile("s_waitcnt vmcnt(0)" ::: "memory");
      PWRITE(bb ^ 1);
    }
    asm volatile("s_waitcnt lgkmcnt(0)" ::: "memory");
    __builtin_amdgcn_s_barrier();
  }

  if (y < 2) {
    short* Out = (y == 0) ? Qs : Ks;
    const float sc = (y == 0) ? scale_q : 1.0f;
    const float bs = bias[n_];
    #pragma unroll
    for (int r = 0; r < 16; ++r) {
      const int row_ = (r & 3) + 8 * (r >> 2) + 4 * hi;
      Out[(m0 + row_) * 128 + n_] = f2bf((acc[r] + bs) * sc);
    }
  } else {
    #pragma unroll
    for (int r = 0; r < 16; ++r) {
      const int dv_ = w * 32 + (r & 3) + 8 * (r >> 2) + 4 * hi;
      VTs[(long)dv_ * 32768 + m0 + l31] = f2bf(acc[r] + bias[dv_]);
    }
  }
}

// ---------------- flash attention, 32x32 MFMA, 4 waves x 32 q-rows, KVBLK=64 ----------------
// Computes O^T[dv][q] partial over a kv-range; writes unnormalized acc + (m,l) stats.
__global__ __launch_bounds__(256, 2) void attn_kernel(
    const short* __restrict__ Q,    // [32768][128] bf16 (pre-scaled by 1/sqrt(128)*log2e)
    const short* __restrict__ K,    // [32768][128] bf16
    const short* __restrict__ VT,   // [128][32768] bf16
    float* __restrict__ O0,         // partial half0 (= d_out)
    float* __restrict__ O1,         // partial half1
    float2* __restrict__ stats,     // [halves][32768] {m, l}
    int ntiles)
{
  __shared__ short lds[32768];      // 2 bufs x (K [64][128] + VT [128][64]) = 64 KB
  const int tid = threadIdx.x, l = tid & 63, w = tid >> 6;
  const int l31 = l & 31, hi = l >> 5, xm = (l & 7) << 3;
  const int qb = blockIdx.x, h = blockIdx.y;
  const int b = qb >> 5;
  const int qrow = qb * 128 + w * 32 + l31;
  const long kv0 = (long)b * 4096 + (long)h * ntiles * 64;

  // Q fragments (B-operand: col = q = l31, k = d = ds*16 + hi*8 + i)
  short8 qf[8];
  const short* Qp = Q + (long)qrow * 128 + hi * 8;
  #pragma unroll
  for (int ds = 0; ds < 8; ++ds) qf[ds] = *(const short8*)(Qp + ds * 16);

  // staging source offsets (inverse-swizzled so linear LDS + swizzled reads match)
  const short* Kt = K + kv0 * 128;
  const short* Vt = VT + kv0;
  int kg_off[4]; long vg_off[4];
  #pragma unroll
  for (int r = 0; r < 4; ++r) {
    int c = r * 256 + tid;
    int p = c * 16;
    kg_off[r] = (p ^ (((p >> 8) & 7) << 4)) >> 1;        // K tile is contiguous [64][128]
    int e = (p ^ (((p >> 7) & 7) << 4)) >> 1;            // VT tile rows stride 32768
    vg_off[r] = (long)(e >> 6) * 32768 + (e & 63);
  }

  #define STAGE(bb, t) { \
    const short* kg_ = Kt + (t) * 8192; \
    const short* vg_ = Vt + (t) * 64; \
    _Pragma("unroll") \
    for (int r = 0; r < 4; ++r) { \
      gload16(kg_ + kg_off[r], &lds[(bb) * 16384 + r * 2048 + w * 512]); \
      gload16(vg_ + vg_off[r], &lds[(bb) * 16384 + 8192 + r * 2048 + w * 512]); \
    } }

  f32x16 acc0 = {}, acc1 = {}, acc2 = {}, acc3 = {};
  float m = -3e38f, lsum = 0.f;
  const int kread = l31 * 128;   // K lds row base (shorts); +4096 for rows 32..63

  STAGE(0, 0);

  for (int t = 0; t < ntiles; ++t) {
    const int bb = t & 1;
    if (t + 1 < ntiles) {
      STAGE(bb ^ 1, t + 1);
      asm volatile("s_waitcnt vmcnt(8)" ::: "memory");   // current tile's 8 done; next 8 in flight
    } else {
      asm volatile("s_waitcnt vmcnt(0)" ::: "memory");
    }
    __builtin_amdgcn_s_barrier();

    const short* kb = &lds[bb * 16384];
    const short* vb = &lds[bb * 16384 + 8192];

    // S^T = K · Q^T : two 32-kv tiles, 8 d-slices of 16
    f32x16 st0 = {}, st1 = {};
    #pragma unroll
    for (int ds = 0; ds < 8; ++ds) {
      int co = (ds * 16 + hi * 8) ^ xm;
      short8 kf0 = *(const short8*)(kb + kread + co);
      short8 kf1 = *(const short8*)(kb + 4096 + kread + co);
      st0 = MFMA32(kf0, qf[ds], st0);
      st1 = MFMA32(kf1, qf[ds], st1);
    }

    // in-register online softmax (lane owns q-column l31; lanes l and l+32 split kv rows)
    float a0 = fmaxf(fmaxf(st0[0], st0[1]),  fmaxf(st0[2], st0[3]));
    float a1 = fmaxf(fmaxf(st0[4], st0[5]),  fmaxf(st0[6], st0[7]));
    float a2 = fmaxf(fmaxf(st0[8], st0[9]),  fmaxf(st0[10], st0[11]));
    float a3 = fmaxf(fmaxf(st0[12], st0[13]), fmaxf(st0[14], st0[15]));
    float b0 = fmaxf(fmaxf(st1[0], st1[1]),  fmaxf(st1[2], st1[3]));
    float b1 = fmaxf(fmaxf(st1[4], st1[5]),  fmaxf(st1[6], st1[7]));
    float b2 = fmaxf(fmaxf(st1[8], st1[9]),  fmaxf(st1[10], st1[11]));
    float b3 = fmaxf(fmaxf(st1[12], st1[13]), fmaxf(st1[14], st1[15]));
    float pm = fmaxf(fmaxf(fmaxf(a0, a1), fmaxf(a2, a3)),
                     fmaxf(fmaxf(b0, b1), fmaxf(b2, b3)));
    pm = fmaxf(pm, __shfl_xor(pm, 32));
    if (!__all(pm <= m + 8.f)) {        // defer-max (T13): skip rescale when growth < 2^8
      float mn = fmaxf(m, pm);
      float al = exp2f(m - mn);
      m = mn;
      lsum *= al;
      acc0 *= al; acc1 *= al; acc2 *= al; acc3 *= al;
    }
    float ts = 0.f;
    #pragma unroll
    for (int j = 0; j < 16; ++j) { st0[j] = exp2f(st0[j] - m); ts += st0[j]; }
    #pragma unroll
    for (int j = 0; j < 16; ++j) { st1[j] = exp2f(st1[j] - m); ts += st1[j]; }
    ts += __shfl_xor(ts, 32);
    lsum += ts;

    // P -> bf16 B-frags: 16 cvt_pk + 8 permlane32_swap (T12)
    unsigned pk[16];
    #pragma unroll
    for (int j = 0; j < 8; ++j) pk[j]     = cvtpk(st0[2 * j], st0[2 * j + 1]);
    #pragma unroll
    for (int j = 0; j < 8; ++j) pk[8 + j] = cvtpk(st1[2 * j], st1[2 * j + 1]);

    // O^T += V^T · P^T : 4 dv-tiles x 4 kv-slices
    #pragma unroll
    for (int f = 0; f < 4; ++f) {
      auto r02 = __builtin_amdgcn_permlane32_swap(pk[f * 4 + 0], pk[f * 4 + 2], false, false);
      auto r13 = __builtin_amdgcn_permlane32_swap(pk[f * 4 + 1], pk[f * 4 + 3], false, false);
      union { u32x4 u; short8 s; } pf;
      pf.u = (u32x4){r02[0], r13[0], r02[1], r13[1]};
      int vo = (f * 16 + hi * 8) ^ xm;
      acc0 = MFMA32(*(const short8*)(vb +        l31 * 64 + vo), pf.s, acc0);
      acc1 = MFMA32(*(const short8*)(vb + 2048 + l31 * 64 + vo), pf.s, acc1);
      acc2 = MFMA32(*(const short8*)(vb + 4096 + l31 * 64 + vo), pf.s, acc2);
      acc3 = MFMA32(*(const short8*)(vb + 6144 + l31 * 64 + vo), pf.s, acc3);
    }

    asm volatile("s_waitcnt lgkmcnt(0)" ::: "memory");
    __builtin_amdgcn_s_barrier();
  }

  float* Op = ((h == 0) ? O0 : O1) + (long)qrow * 128;
  #define STORE_DT(A, dtb) { \
    _Pragma("unroll") \
    for (int jj = 0; jj < 4; ++jj) { \
      f32x4 o_ = {A[4 * jj], A[4 * jj + 1], A[4 * jj + 2], A[4 * jj + 3]}; \
      *(f32x4*)(Op + (dtb) + jj * 8 + hi * 4) = o_; \
    } }
  STORE_DT(acc0, 0) STORE_DT(acc1, 32) STORE_DT(acc2, 64) STORE_DT(acc3, 96)

  if (l < 32) stats[(long)h * 32768 + qrow] = make_float2(m, lsum);
}

// ---------------- merge partial halves ----------------
__global__ __launch_bounds__(256) void merge_kernel(
    float* __restrict__ O, const float* __restrict__ O1,
    const float2* __restrict__ stats, int halves)
{
  int idx = blockIdx.x * 256 + threadIdx.x;   // 32768*32 chunks of f32x4
  int q = idx >> 5, c = (idx & 31) * 4;
  long off = (long)q * 128 + c;
  float2 s0 = stats[q];
  f32x4 a = *(const f32x4*)(O + off);
  if (halves == 2) {
    float2 s1 = stats[32768 + q];
    float M = fmaxf(s0.x, s1.x);
    float w0 = exp2f(s0.x - M), w1 = exp2f(s1.x - M);
    f32x4 bv = *(const f32x4*)(O1 + off);
    float inv = 1.f / (w0 * s0.y + w1 * s1.y);
    a = (a * w0 + bv * w1) * inv;
  } else {
    a = a * (1.f / s0.y);
  }
  *(f32x4*)(O + off) = a;
}

extern "C" void kernel_launch(void* const* d_in, const int* in_sizes, int n_in,
                              void* d_out, int out_size, void* d_ws, size_t ws_size,
                              hipStream_t stream) {
  const float* query = (const float*)d_in[0];
  const float* key   = (const float*)d_in[1];
  const float* value = (const float*)d_in[2];
  const float* Wq = (const float*)d_in[3];
  const float* bq = (const float*)d_in[4];
  const float* Wk = (const float*)d_in[5];
  const float* bk = (const float*)d_in[6];
  const float* Wv = (const float*)d_in[7];
  const float* bv = (const float*)d_in[8];

  char* wsb = (char*)d_ws;
  short* Qs  = (short*)(wsb);                 // 8,388,608 B
  short* Ks  = (short*)(wsb + 8388608);       // 8,388,608 B
  short* VTs = (short*)(wsb + 16777216);      // 8,388,608 B
  short* WqT = (short*)(wsb + 25165824);      // 262,144 B
  short* WkT = (short*)(wsb + 25427968);
  short* WvT = (short*)(wsb + 25690112);      // ends 25,952,256
  float* O1  = (float*)(wsb + 25952256);      // 16,777,216 B (half-1 partial)
  const size_t NEED2 = 25952256ull + 16777216ull + 524288ull;   // 43.3 MB
  int halves = (ws_size >= NEED2) ? 2 : 1;
  float2* stats = (float2*)(wsb + (halves == 2 ? 42729472ull : 25952256ull));
  int ntiles = (halves == 2) ? 32 : 64;

  wt_kernel<<<dim3(512, 3), 256, 0, stream>>>(Wq, Wk, Wv, WqT, WkT, WvT);
  const float scale_q = 0.08838834764831845f * 1.4426950408889634f;  // 1/sqrt(128) * log2(e)
  proj_kernel<<<dim3(1024, 3), 256, 0, stream>>>(query, key, value, WqT, WkT, WvT,
                                                 bq, bk, bv, Qs, Ks, VTs, scale_q);
  attn_kernel<<<dim3(256, halves), 256, 0, stream>>>(Qs, Ks, VTs, (float*)d_out, O1, stats, ntiles);
  merge_kernel<<<4096, 256, 0, stream>>>((float*)d_out, O1, stats, halves);
}

// Round 10
// 230.384 us; speedup vs baseline: 3.0024x; 3.0024x over previous
//
#include <hip/hip_runtime.h>
#include <hip/hip_bf16.h>

typedef __attribute__((ext_vector_type(8))) short short8;
typedef __attribute__((ext_vector_type(4))) float f32x4;
typedef __attribute__((ext_vector_type(16))) float f32x16;
typedef __attribute__((ext_vector_type(4))) unsigned int u32x4;

#define MFMA32(A, B, C) __builtin_amdgcn_mfma_f32_32x32x16_bf16((A), (B), (C), 0, 0, 0)

__device__ __forceinline__ short f2bf(float x) {
  unsigned u = __float_as_uint(x);
  return (short)((u + 0x7FFFu + ((u >> 16) & 1u)) >> 16);  // RNE; inputs finite
}

__device__ __forceinline__ unsigned cvtpk(float lo, float hi) {
  unsigned r;
  asm("v_cvt_pk_bf16_f32 %0, %1, %2" : "=v"(r) : "v"(lo), "v"(hi));
  return r;
}

__device__ __forceinline__ void gload16(const void* g, const void* s) {
  __builtin_amdgcn_global_load_lds(
      (const __attribute__((address_space(1))) unsigned int*)g,
      (__attribute__((address_space(3))) unsigned int*)s, 16, 0, 0);
}

// ---------------- weight transpose + bf16 convert: W[1024][128] -> WT[128][1024] ----------------
__global__ __launch_bounds__(256) void wt_kernel(
    const float* __restrict__ Wq, const float* __restrict__ Wk, const float* __restrict__ Wv,
    short* __restrict__ WqT, short* __restrict__ WkT, short* __restrict__ WvT)
{
  const float* W  = (blockIdx.y == 0) ? Wq  : (blockIdx.y == 1) ? Wk  : Wv;
  short*       WT = (blockIdx.y == 0) ? WqT : (blockIdx.y == 1) ? WkT : WvT;
  int idx = blockIdx.x * 256 + threadIdx.x;   // 0..131071
  int n = idx >> 10, k = idx & 1023;
  WT[idx] = f2bf(W[k * 128 + n]);
}

// ---------------- fused QKV projection: LDS-staged A, occupancy-optimized ----------------
// Block: 32 rows x 128 cols, 4 waves; wave w owns n = w*32 + l31 (one 32x32 acc).
// A tile [32][128] fp32 = 16 KB, double-buffered (32 KB LDS -> 4-5 blocks/CU).
// Per phase: W regs loaded FIRST, then 4 gload16 stage, then vmcnt(4) (retires W + current tile).
// ((row&15)<<4) XOR swizzle on LDS rows; inverse-swizzled staging sources (R7-proven mapping).
__global__ __launch_bounds__(256, 4) void proj_kernel(
    const float* __restrict__ Aq, const float* __restrict__ Ak, const float* __restrict__ Av,
    const short* __restrict__ WqT, const short* __restrict__ WkT, const short* __restrict__ WvT,
    const float* __restrict__ bq, const float* __restrict__ bk, const float* __restrict__ bv,
    short* __restrict__ Qs, short* __restrict__ Ks, short* __restrict__ VTs,
    float scale_q)
{
  __shared__ float lds[8192];   // 32 KB = 2 bufs x (A tile [32][128] fp32 = 16 KB)
  const int y = blockIdx.y;
  const float* A    = (y == 0) ? Aq  : (y == 1) ? Ak  : Av;
  const short* WT   = (y == 0) ? WqT : (y == 1) ? WkT : WvT;
  const float* bias = (y == 0) ? bq  : (y == 1) ? bk  : bv;
  const int tid = threadIdx.x, l = tid & 63, w = tid >> 6;
  const int l31 = l & 31, hi = l >> 5;
  const long m0 = (long)blockIdx.x * 32;

  // staging offsets: instr i covers LDS bytes p = i*4096 + tid*16 (512-B rows);
  // row = p>>9, physical col = p&511, logical (source) col = phys ^ ((row&15)<<4).
  const float* A0 = A + m0 * 1024;
  int ag[4];
  #pragma unroll
  for (int i = 0; i < 4; ++i) {
    const int r_ = i * 8 + (tid >> 5);
    const int cp = (tid & 31) * 16;
    const int cl = cp ^ ((r_ & 15) << 4);
    ag[i] = r_ * 1024 + (cl >> 2);            // float offset into A panel (+kc*128 later)
  }

  #define ASTAGE(bb, kc) { \
    const float* s_ = A0 + (kc) * 128; \
    _Pragma("unroll") \
    for (int i = 0; i < 4; ++i) \
      gload16(s_ + ag[i], (const char*)lds + (bb) * 16384 + i * 4096 + w * 1024); \
  }

  f32x16 acc = {};
  const int n_ = w * 32 + l31;                // this wave's output column (per lane)
  const short* Wn = WT + (long)n_ * 1024 + hi * 8;
  const char* ab0 = (const char*)lds + l31 * 512;
  const int sw = (l31 & 15) << 4;

  ASTAGE(0, 0);

  for (int kc = 0; kc < 8; ++kc) {
    const int bb = kc & 1;
    // W fragments for this phase (L2-resident), issued BEFORE next staging (FIFO-clean)
    short8 wb[8];
    #pragma unroll
    for (int k16 = 0; k16 < 8; ++k16)
      wb[k16] = *(const short8*)(Wn + kc * 128 + k16 * 16);
    if (kc + 1 < 8) {
      ASTAGE(bb ^ 1, kc + 1);
      asm volatile("s_waitcnt vmcnt(4)" ::: "memory");  // retires W + current tile; next 4 in flight
    } else {
      asm volatile("s_waitcnt vmcnt(0)" ::: "memory");
    }
    __builtin_amdgcn_s_barrier();

    const char* ab = ab0 + bb * 16384;
    if (y < 2) {
      #pragma unroll
      for (int k16 = 0; k16 < 8; ++k16) {
        const int ac = k16 * 64 + hi * 32;
        f32x4 a0 = *(const f32x4*)(ab + ((ac)      ^ sw));
        f32x4 a1 = *(const f32x4*)(ab + ((ac + 16) ^ sw));
        short8 af;
        af[0] = f2bf(a0[0]); af[1] = f2bf(a0[1]); af[2] = f2bf(a0[2]); af[3] = f2bf(a0[3]);
        af[4] = f2bf(a1[0]); af[5] = f2bf(a1[1]); af[6] = f2bf(a1[2]); af[7] = f2bf(a1[3]);
        acc = MFMA32(af, wb[k16], acc);
      }
    } else {
      #pragma unroll
      for (int k16 = 0; k16 < 8; ++k16) {
        const int ac = k16 * 64 + hi * 32;
        f32x4 a0 = *(const f32x4*)(ab + ((ac)      ^ sw));
        f32x4 a1 = *(const f32x4*)(ab + ((ac + 16) ^ sw));
        short8 af;
        af[0] = f2bf(a0[0]); af[1] = f2bf(a0[1]); af[2] = f2bf(a0[2]); af[3] = f2bf(a0[3]);
        af[4] = f2bf(a1[0]); af[5] = f2bf(a1[1]); af[6] = f2bf(a1[2]); af[7] = f2bf(a1[3]);
        // V^T: A-operand = W^T rows (dv), B-operand = value rows as columns
        acc = MFMA32(wb[k16], af, acc);
      }
    }
    __builtin_amdgcn_s_barrier();
  }

  if (y < 2) {
    short* Out = (y == 0) ? Qs : Ks;
    const float sc = (y == 0) ? scale_q : 1.0f;
    const float bs = bias[n_];
    #pragma unroll
    for (int r = 0; r < 16; ++r) {
      const int row_ = (r & 3) + 8 * (r >> 2) + 4 * hi;
      Out[(m0 + row_) * 128 + n_] = f2bf((acc[r] + bs) * sc);
    }
  } else {
    #pragma unroll
    for (int r = 0; r < 16; ++r) {
      const int dv_ = w * 32 + (r & 3) + 8 * (r >> 2) + 4 * hi;
      VTs[(long)dv_ * 32768 + m0 + l31] = f2bf(acc[r] + bias[dv_]);
    }
  }
}

// ---------------- flash attention, 32x32 MFMA, 4 waves x 32 q-rows, KVBLK=64 ----------------
// Computes O^T[dv][q] partial over a kv-range; writes unnormalized acc + (m,l) stats.
__global__ __launch_bounds__(256, 2) void attn_kernel(
    const short* __restrict__ Q,    // [32768][128] bf16 (pre-scaled by 1/sqrt(128)*log2e)
    const short* __restrict__ K,    // [32768][128] bf16
    const short* __restrict__ VT,   // [128][32768] bf16
    float* __restrict__ O0,         // partial half0 (= d_out)
    float* __restrict__ O1,         // partial half1
    float2* __restrict__ stats,     // [halves][32768] {m, l}
    int ntiles)
{
  __shared__ short lds[32768];      // 2 bufs x (K [64][128] + VT [128][64]) = 64 KB
  const int tid = threadIdx.x, l = tid & 63, w = tid >> 6;
  const int l31 = l & 31, hi = l >> 5, xm = (l & 7) << 3;
  const int qb = blockIdx.x, h = blockIdx.y;
  const int b = qb >> 5;
  const int qrow = qb * 128 + w * 32 + l31;
  const long kv0 = (long)b * 4096 + (long)h * ntiles * 64;

  // Q fragments (B-operand: col = q = l31, k = d = ds*16 + hi*8 + i)
  short8 qf[8];
  const short* Qp = Q + (long)qrow * 128 + hi * 8;
  #pragma unroll
  for (int ds = 0; ds < 8; ++ds) qf[ds] = *(const short8*)(Qp + ds * 16);

  // staging source offsets (inverse-swizzled so linear LDS + swizzled reads match)
  const short* Kt = K + kv0 * 128;
  const short* Vt = VT + kv0;
  int kg_off[4]; long vg_off[4];
  #pragma unroll
  for (int r = 0; r < 4; ++r) {
    int c = r * 256 + tid;
    int p = c * 16;
    kg_off[r] = (p ^ (((p >> 8) & 7) << 4)) >> 1;        // K tile is contiguous [64][128]
    int e = (p ^ (((p >> 7) & 7) << 4)) >> 1;            // VT tile rows stride 32768
    vg_off[r] = (long)(e >> 6) * 32768 + (e & 63);
  }

  #define STAGE(bb, t) { \
    const short* kg_ = Kt + (t) * 8192; \
    const short* vg_ = Vt + (t) * 64; \
    _Pragma("unroll") \
    for (int r = 0; r < 4; ++r) { \
      gload16(kg_ + kg_off[r], &lds[(bb) * 16384 + r * 2048 + w * 512]); \
      gload16(vg_ + vg_off[r], &lds[(bb) * 16384 + 8192 + r * 2048 + w * 512]); \
    } }

  f32x16 acc0 = {}, acc1 = {}, acc2 = {}, acc3 = {};
  float m = -3e38f, lsum = 0.f;
  const int kread = l31 * 128;   // K lds row base (shorts); +4096 for rows 32..63

  STAGE(0, 0);

  for (int t = 0; t < ntiles; ++t) {
    const int bb = t & 1;
    if (t + 1 < ntiles) {
      STAGE(bb ^ 1, t + 1);
      asm volatile("s_waitcnt vmcnt(8)" ::: "memory");   // current tile's 8 done; next 8 in flight
    } else {
      asm volatile("s_waitcnt vmcnt(0)" ::: "memory");
    }
    __builtin_amdgcn_s_barrier();

    const short* kb = &lds[bb * 16384];
    const short* vb = &lds[bb * 16384 + 8192];

    // S^T = K · Q^T : two 32-kv tiles, 8 d-slices of 16
    f32x16 st0 = {}, st1 = {};
    #pragma unroll
    for (int ds = 0; ds < 8; ++ds) {
      int co = (ds * 16 + hi * 8) ^ xm;
      short8 kf0 = *(const short8*)(kb + kread + co);
      short8 kf1 = *(const short8*)(kb + 4096 + kread + co);
      st0 = MFMA32(kf0, qf[ds], st0);
      st1 = MFMA32(kf1, qf[ds], st1);
    }

    // in-register online softmax (lane owns q-column l31; lanes l and l+32 split kv rows)
    float a0 = fmaxf(fmaxf(st0[0], st0[1]),  fmaxf(st0[2], st0[3]));
    float a1 = fmaxf(fmaxf(st0[4], st0[5]),  fmaxf(st0[6], st0[7]));
    float a2 = fmaxf(fmaxf(st0[8], st0[9]),  fmaxf(st0[10], st0[11]));
    float a3 = fmaxf(fmaxf(st0[12], st0[13]), fmaxf(st0[14], st0[15]));
    float b0 = fmaxf(fmaxf(st1[0], st1[1]),  fmaxf(st1[2], st1[3]));
    float b1 = fmaxf(fmaxf(st1[4], st1[5]),  fmaxf(st1[6], st1[7]));
    float b2 = fmaxf(fmaxf(st1[8], st1[9]),  fmaxf(st1[10], st1[11]));
    float b3 = fmaxf(fmaxf(st1[12], st1[13]), fmaxf(st1[14], st1[15]));
    float pm = fmaxf(fmaxf(fmaxf(a0, a1), fmaxf(a2, a3)),
                     fmaxf(fmaxf(b0, b1), fmaxf(b2, b3)));
    pm = fmaxf(pm, __shfl_xor(pm, 32));
    if (!__all(pm <= m + 8.f)) {        // defer-max (T13): skip rescale when growth < 2^8
      float mn = fmaxf(m, pm);
      float al = exp2f(m - mn);
      m = mn;
      lsum *= al;
      acc0 *= al; acc1 *= al; acc2 *= al; acc3 *= al;
    }
    float ts = 0.f;
    #pragma unroll
    for (int j = 0; j < 16; ++j) { st0[j] = exp2f(st0[j] - m); ts += st0[j]; }
    #pragma unroll
    for (int j = 0; j < 16; ++j) { st1[j] = exp2f(st1[j] - m); ts += st1[j]; }
    ts += __shfl_xor(ts, 32);
    lsum += ts;

    // P -> bf16 B-frags: 16 cvt_pk + 8 permlane32_swap (T12)
    unsigned pk[16];
    #pragma unroll
    for (int j = 0; j < 8; ++j) pk[j]     = cvtpk(st0[2 * j], st0[2 * j + 1]);
    #pragma unroll
    for (int j = 0; j < 8; ++j) pk[8 + j] = cvtpk(st1[2 * j], st1[2 * j + 1]);

    // O^T += V^T · P^T : 4 dv-tiles x 4 kv-slices
    #pragma unroll
    for (int f = 0; f < 4; ++f) {
      auto r02 = __builtin_amdgcn_permlane32_swap(pk[f * 4 + 0], pk[f * 4 + 2], false, false);
      auto r13 = __builtin_amdgcn_permlane32_swap(pk[f * 4 + 1], pk[f * 4 + 3], false, false);
      union { u32x4 u; short8 s; } pf;
      pf.u = (u32x4){r02[0], r13[0], r02[1], r13[1]};
      int vo = (f * 16 + hi * 8) ^ xm;
      acc0 = MFMA32(*(const short8*)(vb +        l31 * 64 + vo), pf.s, acc0);
      acc1 = MFMA32(*(const short8*)(vb + 2048 + l31 * 64 + vo), pf.s, acc1);
      acc2 = MFMA32(*(const short8*)(vb + 4096 + l31 * 64 + vo), pf.s, acc2);
      acc3 = MFMA32(*(const short8*)(vb + 6144 + l31 * 64 + vo), pf.s, acc3);
    }

    asm volatile("s_waitcnt lgkmcnt(0)" ::: "memory");
    __builtin_amdgcn_s_barrier();
  }

  float* Op = ((h == 0) ? O0 : O1) + (long)qrow * 128;
  #define STORE_DT(A, dtb) { \
    _Pragma("unroll") \
    for (int jj = 0; jj < 4; ++jj) { \
      f32x4 o_ = {A[4 * jj], A[4 * jj + 1], A[4 * jj + 2], A[4 * jj + 3]}; \
      *(f32x4*)(Op + (dtb) + jj * 8 + hi * 4) = o_; \
    } }
  STORE_DT(acc0, 0) STORE_DT(acc1, 32) STORE_DT(acc2, 64) STORE_DT(acc3, 96)

  if (l < 32) stats[(long)h * 32768 + qrow] = make_float2(m, lsum);
}

// ---------------- merge partial halves ----------------
__global__ __launch_bounds__(256) void merge_kernel(
    float* __restrict__ O, const float* __restrict__ O1,
    const float2* __restrict__ stats, int halves)
{
  int idx = blockIdx.x * 256 + threadIdx.x;   // 32768*32 chunks of f32x4
  int q = idx >> 5, c = (idx & 31) * 4;
  long off = (long)q * 128 + c;
  float2 s0 = stats[q];
  f32x4 a = *(const f32x4*)(O + off);
  if (halves == 2) {
    float2 s1 = stats[32768 + q];
    float M = fmaxf(s0.x, s1.x);
    float w0 = exp2f(s0.x - M), w1 = exp2f(s1.x - M);
    f32x4 bv = *(const f32x4*)(O1 + off);
    float inv = 1.f / (w0 * s0.y + w1 * s1.y);
    a = (a * w0 + bv * w1) * inv;
  } else {
    a = a * (1.f / s0.y);
  }
  *(f32x4*)(O + off) = a;
}

extern "C" void kernel_launch(void* const* d_in, const int* in_sizes, int n_in,
                              void* d_out, int out_size, void* d_ws, size_t ws_size,
                              hipStream_t stream) {
  const float* query = (const float*)d_in[0];
  const float* key   = (const float*)d_in[1];
  const float* value = (const float*)d_in[2];
  const float* Wq = (const float*)d_in[3];
  const float* bq = (const float*)d_in[4];
  const float* Wk = (const float*)d_in[5];
  const float* bk = (const float*)d_in[6];
  const float* Wv = (const float*)d_in[7];
  const float* bv = (const float*)d_in[8];

  char* wsb = (char*)d_ws;
  short* Qs  = (short*)(wsb);                 // 8,388,608 B
  short* Ks  = (short*)(wsb + 8388608);       // 8,388,608 B
  short* VTs = (short*)(wsb + 16777216);      // 8,388,608 B
  short* WqT = (short*)(wsb + 25165824);      // 262,144 B
  short* WkT = (short*)(wsb + 25427968);
  short* WvT = (short*)(wsb + 25690112);      // ends 25,952,256
  float* O1  = (float*)(wsb + 25952256);      // 16,777,216 B (half-1 partial)
  const size_t NEED2 = 25952256ull + 16777216ull + 524288ull;   // 43.3 MB
  int halves = (ws_size >= NEED2) ? 2 : 1;
  float2* stats = (float2*)(wsb + (halves == 2 ? 42729472ull : 25952256ull));
  int ntiles = (halves == 2) ? 32 : 64;

  wt_kernel<<<dim3(512, 3), 256, 0, stream>>>(Wq, Wk, Wv, WqT, WkT, WvT);
  const float scale_q = 0.08838834764831845f * 1.4426950408889634f;  // 1/sqrt(128) * log2(e)
  proj_kernel<<<dim3(1024, 3), 256, 0, stream>>>(query, key, value, WqT, WkT, WvT,
                                                 bq, bk, bv, Qs, Ks, VTs, scale_q);
  attn_kernel<<<dim3(256, halves), 256, 0, stream>>>(Qs, Ks, VTs, (float*)d_out, O1, stats, ntiles);
  merge_kernel<<<4096, 256, 0, stream>>>((float*)d_out, O1, stats, halves);
}